// Round 1
// baseline (1407.961 us; speedup 1.0000x reference)
//
#include <hip/hip_runtime.h>
#include <hip/hip_bf16.h>
#include <math.h>

// ---------------- constants ----------------
#define SEQ_LEN 8
#define D_IN 2048
#define D_OUT 1152
#define TSS 3
#define WAY 5
#define SHOT 5
#define N_SUPPORT 25
#define N_Q 100
#define N_SEQ 125          // N_SUPPORT + N_Q
#define N_ROWS 1000        // N_SEQ * SEQ_LEN
#define T_LEN 56
#define KS_LEN 280         // SHOT * T_LEN
#define NCOLS 6912         // 6 * D_OUT  (3 slots x {k,v})

__constant__ int TUP[T_LEN][3] = {
  {0,1,2},{0,1,3},{0,1,4},{0,1,5},{0,1,6},{0,1,7},{0,2,3},{0,2,4},{0,2,5},{0,2,6},
  {0,2,7},{0,3,4},{0,3,5},{0,3,6},{0,3,7},{0,4,5},{0,4,6},{0,4,7},{0,5,6},{0,5,7},
  {0,6,7},{1,2,3},{1,2,4},{1,2,5},{1,2,6},{1,2,7},{1,3,4},{1,3,5},{1,3,6},{1,3,7},
  {1,4,5},{1,4,6},{1,4,7},{1,5,6},{1,5,7},{1,6,7},{2,3,4},{2,3,5},{2,3,6},{2,3,7},
  {2,4,5},{2,4,6},{2,4,7},{2,5,6},{2,5,7},{2,6,7},{3,4,5},{3,4,6},{3,4,7},{3,5,6},
  {3,5,7},{3,6,7},{4,5,6},{4,5,7},{4,6,7},{5,6,7}
};

// ---------------- kernel 0: X = input + PE ----------------
__global__ __launch_bounds__(256) void pe_add(const float* __restrict__ sup,
                                              const float* __restrict__ que,
                                              float* __restrict__ X) {
  int idx = blockIdx.x * 256 + threadIdx.x;
  if (idx >= N_ROWS * D_IN) return;
  int d = idx & (D_IN - 1);
  int r = idx >> 11;
  int i = r & 7;
  int h2 = d & ~1;
  float freq = expf((float)h2 * (-9.210340371976184f / (float)D_IN)); // ln(10000)
  float ang = (float)i * freq;
  float pe = ((d & 1) ? cosf(ang) : sinf(ang)) * 0.1f;
  float src = (r < N_SUPPORT * SEQ_LEN) ? sup[idx] : que[idx - N_SUPPORT * SEQ_LEN * D_IN];
  X[idx] = src + pe;
}

// ---------------- kernel 1: G = X @ W  (W gathered from k_w/v_w blocks) ----
// G[r, b*1152 + n] ; b = 2*j + kv ; column tile never crosses a b-block.
#define BM 64
#define BN 64
#define BK 16
__global__ __launch_bounds__(256) void gemm_proj(const float* __restrict__ X,
                                                 const float* __restrict__ k_w,
                                                 const float* __restrict__ v_w,
                                                 float* __restrict__ G) {
  int gx = blockIdx.x;              // 0..107
  int gy = blockIdx.y;              // 0..15
  int b  = gx / 18;                 // 0..5
  int col0 = (gx % 18) * BN;        // within D_OUT
  int j = b >> 1;
  const float* W = ((b & 1) ? v_w : k_w) + (size_t)j * 2048 * D_OUT;
  int row0 = gy * BM;
  __shared__ float As[BK][BM];
  __shared__ float Bs[BK][BN];
  int tid = threadIdx.x;
  float acc[4][4] = {};
  int tm = (tid >> 4) * 4;
  int tn = (tid & 15) * 4;
  for (int k0 = 0; k0 < D_IN; k0 += BK) {
    // A tile: 64 rows x 16 k
    {
      int m = tid >> 2;
      int kq = (tid & 3) * 4;
      int r = row0 + m;
      float4 a4 = (r < N_ROWS) ? *(const float4*)(X + (size_t)r * D_IN + k0 + kq)
                               : make_float4(0.f, 0.f, 0.f, 0.f);
      As[kq + 0][m] = a4.x; As[kq + 1][m] = a4.y;
      As[kq + 2][m] = a4.z; As[kq + 3][m] = a4.w;
    }
    // B tile: 16 k x 64 n
    {
      int k = tid >> 4;
      int n4 = (tid & 15) * 4;
      *(float4*)&Bs[k][n4] = *(const float4*)(W + (size_t)(k0 + k) * D_OUT + col0 + n4);
    }
    __syncthreads();
#pragma unroll
    for (int k = 0; k < BK; ++k) {
      float4 a4 = *(const float4*)&As[k][tm];
      float4 b4 = *(const float4*)&Bs[k][tn];
      float a[4] = {a4.x, a4.y, a4.z, a4.w};
      float bb[4] = {b4.x, b4.y, b4.z, b4.w};
#pragma unroll
      for (int i = 0; i < 4; ++i)
#pragma unroll
        for (int jj = 0; jj < 4; ++jj) acc[i][jj] += a[i] * bb[jj];
    }
    __syncthreads();
  }
#pragma unroll
  for (int i = 0; i < 4; ++i) {
    int r = row0 + tm + i;
    if (r < N_ROWS) {
      float* dst = G + (size_t)r * NCOLS + b * D_OUT + col0 + tn;
#pragma unroll
      for (int jj = 0; jj < 4; ++jj) dst[jj] = acc[i][jj];
    }
  }
}

// ---------------- kernel 2: tuple-combine + bias + LayerNorm(K) -----------
__global__ __launch_bounds__(256) void combine_ln(const float* __restrict__ G,
                                                  const float* __restrict__ kb,
                                                  const float* __restrict__ vb,
                                                  const float* __restrict__ lng,
                                                  const float* __restrict__ lnb,
                                                  float* __restrict__ skln,
                                                  float* __restrict__ qkln,
                                                  float* __restrict__ sv,
                                                  float* __restrict__ qv) {
  int t = blockIdx.x;   // 0..55
  int n = blockIdx.y;   // 0..124
  const float* g0 = G + (size_t)(n * 8 + TUP[t][0]) * NCOLS;
  const float* g1 = G + (size_t)(n * 8 + TUP[t][1]) * NCOLS;
  const float* g2 = G + (size_t)(n * 8 + TUP[t][2]) * NCOLS;
  __shared__ float kbuf[D_OUT];
  __shared__ float red1[256], red2[256];
  int tid = threadIdx.x;
  bool isq = (n >= N_SUPPORT);
  size_t orow = isq ? ((size_t)(n - N_SUPPORT) * T_LEN + t) * D_OUT
                    : ((size_t)n * T_LEN + t) * D_OUT;
  float* vout = (isq ? qv : sv) + orow;
  float s1 = 0.f, s2 = 0.f;
  for (int d = tid; d < D_OUT; d += 256) {
    float kvv = g0[d] + g1[2 * D_OUT + d] + g2[4 * D_OUT + d] + kb[d];
    float vvv = g0[D_OUT + d] + g1[3 * D_OUT + d] + g2[5 * D_OUT + d] + vb[d];
    kbuf[d] = kvv;
    vout[d] = vvv;
    s1 += kvv;
    s2 += kvv * kvv;
  }
  red1[tid] = s1; red2[tid] = s2;
  __syncthreads();
  for (int s = 128; s > 0; s >>= 1) {
    if (tid < s) { red1[tid] += red1[tid + s]; red2[tid] += red2[tid + s]; }
    __syncthreads();
  }
  float mu = red1[0] * (1.0f / D_OUT);
  float var = red2[0] * (1.0f / D_OUT) - mu * mu;
  float rs = rsqrtf(var + 1e-5f);
  float* kout = (isq ? qkln : skln) + orow;
  for (int d = tid; d < D_OUT; d += 256) {
    kout[d] = (kbuf[d] - mu) * rs * lng[d] + lnb[d];
  }
}

// ---------------- kernel 3: fused attention ------------------------------
// block: 8 t-rows of one q, one class. scores -> softmax -> proto -> dist.
__global__ __launch_bounds__(256) void attn(const float* __restrict__ skln,
                                            const float* __restrict__ qkln,
                                            const float* __restrict__ sv,
                                            const float* __restrict__ qv,
                                            float* __restrict__ distpart,
                                            float* __restrict__ out_align) {
  int tb = blockIdx.x;  // 0..6  -> t0 = tb*8
  int q  = blockIdx.y;  // 0..99
  int c  = blockIdx.z;  // 0..4
  int t0 = tb * 8;
  __shared__ float qs[8][D_OUT];
  __shared__ float sms[8][KS_LEN];
  __shared__ float red[256];
  int tid = threadIdx.x;
  for (int idx = tid; idx < 8 * D_OUT; idx += 256) {
    int r = idx / D_OUT, d = idx - r * D_OUT;
    qs[r][d] = qkln[((size_t)q * T_LEN + t0 + r) * D_OUT + d];
  }
  __syncthreads();
  const float scale = 0.02946278254943948f; // 1/sqrt(1152)
  // scores: sms[r][ks] = qk[r] . class_k[ks] * scale
  for (int ks = tid; ks < KS_LEN; ks += 256) {
    const float4* ck = (const float4*)(skln + ((size_t)c * KS_LEN + ks) * D_OUT);
    float acc[8] = {};
    for (int d4 = 0; d4 < D_OUT / 4; ++d4) {
      float4 cv = ck[d4];
#pragma unroll
      for (int r = 0; r < 8; ++r) {
        float4 q4 = *((const float4*)&qs[r][0] + d4);
        acc[r] += q4.x * cv.x + q4.y * cv.y + q4.z * cv.z + q4.w * cv.w;
      }
    }
#pragma unroll
    for (int r = 0; r < 8; ++r) sms[r][ks] = acc[r] * scale;
  }
  __syncthreads();
  // softmax per row over 280: 8 groups of 32 lanes
  {
    int r = tid >> 5, g = tid & 31;
    float mx = -1e30f;
    for (int ks = g; ks < KS_LEN; ks += 32) mx = fmaxf(mx, sms[r][ks]);
#pragma unroll
    for (int m = 16; m > 0; m >>= 1) mx = fmaxf(mx, __shfl_xor(mx, m));
    float sum = 0.f;
    for (int ks = g; ks < KS_LEN; ks += 32) {
      float p = expf(sms[r][ks] - mx);
      sms[r][ks] = p;
      sum += p;
    }
#pragma unroll
    for (int m = 16; m > 0; m >>= 1) sum += __shfl_xor(sum, m);
    float inv = 1.0f / sum;
    for (int ks = g; ks < KS_LEN; ks += 32) sms[r][ks] *= inv;
  }
  __syncthreads();
  // align output (class 4 only): align[q,t,s] = sum_k sm[t][k*56+s]
  if (c == WAY - 1) {
    for (int idx = tid; idx < 8 * T_LEN; idx += 256) {
      int r = idx / T_LEN, s = idx - r * T_LEN;
      float a = 0.f;
#pragma unroll
      for (int k = 0; k < SHOT; ++k) a += sms[r][k * T_LEN + s];
      out_align[(size_t)q * T_LEN * T_LEN + (size_t)(t0 + r) * T_LEN + s] = a;
    }
  }
  // proto + diff^2
  float sq[8] = {};
  for (int dbase = tid * 4; dbase < D_OUT; dbase += 1024) {
    float4 p[8] = {};
    const float* cvb = sv + (size_t)c * KS_LEN * D_OUT + dbase;
    for (int ks = 0; ks < KS_LEN; ++ks) {
      float4 v4 = *(const float4*)(cvb + (size_t)ks * D_OUT);
#pragma unroll
      for (int r = 0; r < 8; ++r) {
        float sm = sms[r][ks];
        p[r].x += sm * v4.x; p[r].y += sm * v4.y;
        p[r].z += sm * v4.z; p[r].w += sm * v4.w;
      }
    }
#pragma unroll
    for (int r = 0; r < 8; ++r) {
      float4 q4 = *(const float4*)(qv + ((size_t)q * T_LEN + t0 + r) * D_OUT + dbase);
      float dx = q4.x - p[r].x, dy = q4.y - p[r].y;
      float dz = q4.z - p[r].z, dw = q4.w - p[r].w;
      sq[r] += dx * dx + dy * dy + dz * dz + dw * dw;
    }
  }
  for (int r = 0; r < 8; ++r) {
    red[tid] = sq[r];
    __syncthreads();
    for (int s = 128; s > 0; s >>= 1) {
      if (tid < s) red[tid] += red[tid + s];
      __syncthreads();
    }
    if (tid == 0) distpart[((size_t)q * WAY + c) * T_LEN + t0 + r] = red[0];
    __syncthreads();
  }
}

// ---------------- kernel 4: logits = -sum_t dist / 56 --------------------
__global__ __launch_bounds__(256) void logits_k(const float* __restrict__ distpart,
                                                float* __restrict__ out) {
  int i = blockIdx.x * 256 + threadIdx.x; // q*5+c
  if (i >= N_Q * WAY) return;
  float s = 0.f;
  for (int t = 0; t < T_LEN; ++t) s += distpart[(size_t)i * T_LEN + t];
  out[i] = -s * (1.0f / T_LEN);
}

// ---------------- launch ----------------
extern "C" void kernel_launch(void* const* d_in, const int* in_sizes, int n_in,
                              void* d_out, int out_size, void* d_ws, size_t ws_size,
                              hipStream_t stream) {
  const float* sup  = (const float*)d_in[0];
  const float* que  = (const float*)d_in[1];
  const float* k_w  = (const float*)d_in[3];
  const float* k_b  = (const float*)d_in[4];
  const float* v_w  = (const float*)d_in[5];
  const float* v_b  = (const float*)d_in[6];
  const float* ln_g = (const float*)d_in[7];
  const float* ln_b = (const float*)d_in[8];
  float* out = (float*)d_out;

  float* ws = (float*)d_ws;
  float* X        = ws;                  // 2,048,000
  float* G        = X + 2048000;         // 6,912,000
  float* skln     = G + 6912000;         // 1,612,800
  float* qkln     = skln + 1612800;      // 6,451,200
  float* sv       = qkln + 6451200;      // 1,612,800
  float* qv       = sv + 1612800;        // 6,451,200
  float* distpart = qv + 6451200;        // 28,000

  pe_add<<<dim3((N_ROWS * D_IN + 255) / 256), 256, 0, stream>>>(sup, que, X);
  gemm_proj<<<dim3(108, 16), 256, 0, stream>>>(X, k_w, v_w, G);
  combine_ln<<<dim3(T_LEN, N_SEQ), 256, 0, stream>>>(G, k_b, v_b, ln_g, ln_b,
                                                     skln, qkln, sv, qv);
  attn<<<dim3(7, N_Q, WAY), 256, 0, stream>>>(skln, qkln, sv, qv, distpart,
                                              out + N_Q * WAY);
  logits_k<<<dim3(2), 256, 0, stream>>>(distpart, out);
}

// Round 2
// 260.657 us; speedup vs baseline: 5.4016x; 5.4016x over previous
//
#include <hip/hip_runtime.h>
#include <hip/hip_bf16.h>
#include <math.h>

// ---------------- constants ----------------
#define SEQ_LEN 8
#define D_IN 2048
#define D_OUT 1152
#define WAY 5
#define SHOT 5
#define N_SUPPORT 25
#define N_Q 100
#define N_SEQ 125
#define N_ROWS 1000        // N_SEQ * SEQ_LEN
#define T_LEN 56
#define KS_LEN 280         // SHOT * T_LEN
#define KS_PAD 288         // padded to 16-multiple (and 32-mult for K)
#define NCOLS 6912         // 6 * D_OUT
#define MQT 5600           // N_Q * T_LEN
#define NCT 18             // 1152/64 col tiles in proto

typedef __attribute__((ext_vector_type(4))) float f32x4;
typedef __attribute__((ext_vector_type(8))) short bf16x8;

__constant__ int TUP[T_LEN][3] = {
  {0,1,2},{0,1,3},{0,1,4},{0,1,5},{0,1,6},{0,1,7},{0,2,3},{0,2,4},{0,2,5},{0,2,6},
  {0,2,7},{0,3,4},{0,3,5},{0,3,6},{0,3,7},{0,4,5},{0,4,6},{0,4,7},{0,5,6},{0,5,7},
  {0,6,7},{1,2,3},{1,2,4},{1,2,5},{1,2,6},{1,2,7},{1,3,4},{1,3,5},{1,3,6},{1,3,7},
  {1,4,5},{1,4,6},{1,4,7},{1,5,6},{1,5,7},{1,6,7},{2,3,4},{2,3,5},{2,3,6},{2,3,7},
  {2,4,5},{2,4,6},{2,4,7},{2,5,6},{2,5,7},{2,6,7},{3,4,5},{3,4,6},{3,4,7},{3,5,6},
  {3,5,7},{3,6,7},{4,5,6},{4,5,7},{4,6,7},{5,6,7}
};

// ---------------- kernel 0: Xbf = (input + PE) as bf16 ----------------
__global__ __launch_bounds__(256) void pe_add(const float* __restrict__ sup,
                                              const float* __restrict__ que,
                                              __hip_bfloat16* __restrict__ X) {
  int idx = blockIdx.x * 256 + threadIdx.x;
  if (idx >= N_ROWS * D_IN) return;
  int d = idx & (D_IN - 1);
  int r = idx >> 11;
  int i = r & 7;
  int h2 = d & ~1;
  float freq = expf((float)h2 * (-9.210340371976184f / (float)D_IN)); // ln(10000)
  float ang = (float)i * freq;
  float pe = ((d & 1) ? cosf(ang) : sinf(ang)) * 0.1f;
  float src = (r < N_SUPPORT * SEQ_LEN) ? sup[idx] : que[idx - N_SUPPORT * SEQ_LEN * D_IN];
  X[idx] = __float2bfloat16(src + pe);
}

// ---------------- kernel 1: WT[b*1152+n][k] = W_b[k][n] (bf16) -----------
__global__ __launch_bounds__(256) void wtrans(const float* __restrict__ kw,
                                              const float* __restrict__ vw,
                                              __hip_bfloat16* __restrict__ WT) {
  __shared__ float tile[64][65];
  int bx = blockIdx.x;              // 108 n-tiles (6 b-blocks x 18)
  int by = blockIdx.y;              // 32 k-tiles
  int b = bx / 18;
  int n0 = (bx % 18) * 64;
  int k0 = by * 64;
  const float* src = ((b & 1) ? vw : kw) + (size_t)(b >> 1) * D_IN * D_OUT;
#pragma unroll
  for (int it = 0; it < 16; ++it) {
    int lin = it * 256 + threadIdx.x;
    int kk = lin >> 6, nn = lin & 63;
    tile[kk][nn] = src[(size_t)(k0 + kk) * D_OUT + n0 + nn];
  }
  __syncthreads();
#pragma unroll
  for (int it = 0; it < 16; ++it) {
    int lin = it * 256 + threadIdx.x;
    int nn = lin >> 6, kk = lin & 63;
    WT[((size_t)(b * D_OUT + n0 + nn)) * D_IN + k0 + kk] = __float2bfloat16(tile[kk][nn]);
  }
}

// ---------------- generic bt-form MFMA GEMM: C = A(MxK) * BT(NxK)^T ------
// EPI 0: C fp32 store. EPI 1: C fp32 store * alpha. EPI 2: proto+dist.
template<int EPI>
__global__ __launch_bounds__(256) void gemm_bt(
    const __hip_bfloat16* __restrict__ A, const __hip_bfloat16* __restrict__ BT,
    float* __restrict__ C,
    const __hip_bfloat16* __restrict__ QV, float* __restrict__ DP,
    int M, int N, int K, int lda, int ldb, int ldc, float alpha,
    int batchA, int batchB, int batchC) {
  int z = blockIdx.z;
  A  += (size_t)z * batchA;
  BT += (size_t)z * batchB;
  if constexpr (EPI < 2) C += (size_t)z * batchC;
  else                   DP += (size_t)z * batchC;

  int row0 = blockIdx.x * 64;
  int col0 = blockIdx.y * 64;

  __shared__ __align__(16) ushort As[64][40];   // 32 + 8 pad (keeps 16B align)
  __shared__ __align__(16) ushort Bs[64][40];

  int tid = threadIdx.x;
  int wid = tid >> 6, lane = tid & 63;
  int l16 = lane & 15, lk = lane >> 4;
  int srow = tid >> 2;
  int skq = (tid & 3) * 8;

  f32x4 acc[4] = {};
  for (int k0 = 0; k0 < K; k0 += 32) {
    // stage A tile (64 x 32)
    {
      int ar = row0 + srow;
      uint4 v = make_uint4(0u, 0u, 0u, 0u);
      if (ar < M) v = *(const uint4*)(A + (size_t)ar * lda + k0 + skq);
      *(uint4*)&As[srow][skq] = v;
    }
    // stage BT tile (64 x 32)
    {
      int br = col0 + srow;
      uint4 v = make_uint4(0u, 0u, 0u, 0u);
      if (br < N) v = *(const uint4*)(BT + (size_t)br * ldb + k0 + skq);
      *(uint4*)&Bs[srow][skq] = v;
    }
    __syncthreads();
    bf16x8 af = *(const bf16x8*)&As[wid * 16 + l16][lk * 8];
#pragma unroll
    for (int j = 0; j < 4; ++j) {
      bf16x8 bfv = *(const bf16x8*)&Bs[j * 16 + l16][lk * 8];
      acc[j] = __builtin_amdgcn_mfma_f32_16x16x32_bf16(af, bfv, acc[j], 0, 0, 0);
    }
    __syncthreads();
  }

  if constexpr (EPI < 2) {
#pragma unroll
    for (int j = 0; j < 4; ++j) {
      int col = col0 + j * 16 + l16;
#pragma unroll
      for (int r = 0; r < 4; ++r) {
        int row = row0 + wid * 16 + lk * 4 + r;
        if (row < M && col < N)
          C[(size_t)row * ldc + col] = (EPI == 1) ? acc[j][r] * alpha : acc[j][r];
      }
    }
  } else {
    // proto + dist: sq[r] = sum over this tile's cols of (qv - proto)^2
    float sq[4] = {0.f, 0.f, 0.f, 0.f};
#pragma unroll
    for (int j = 0; j < 4; ++j) {
      int col = col0 + j * 16 + l16;           // < 1152 always
#pragma unroll
      for (int r = 0; r < 4; ++r) {
        int row = row0 + wid * 16 + lk * 4 + r;
        if (row < M) {
          float qvv = __bfloat162float(QV[(size_t)row * D_OUT + col]);
          float d = qvv - acc[j][r];
          sq[r] += d * d;
        }
      }
    }
#pragma unroll
    for (int r = 0; r < 4; ++r) {
      sq[r] += __shfl_xor(sq[r], 1);
      sq[r] += __shfl_xor(sq[r], 2);
      sq[r] += __shfl_xor(sq[r], 4);
      sq[r] += __shfl_xor(sq[r], 8);
    }
    if (l16 == 0) {
#pragma unroll
      for (int r = 0; r < 4; ++r) {
        int row = row0 + wid * 16 + lk * 4 + r;
        if (row < M) DP[(size_t)row * NCT + blockIdx.y] = sq[r];
      }
    }
  }
}

// ---------------- kernel 2: tuple-combine + bias + LayerNorm(K) -----------
__global__ __launch_bounds__(256) void combine_ln(const float* __restrict__ G,
                                                  const float* __restrict__ kb,
                                                  const float* __restrict__ vb,
                                                  const float* __restrict__ lng,
                                                  const float* __restrict__ lnb,
                                                  __hip_bfloat16* __restrict__ skbf,
                                                  __hip_bfloat16* __restrict__ qkbf,
                                                  __hip_bfloat16* __restrict__ svT,
                                                  __hip_bfloat16* __restrict__ qvbf) {
  int t = blockIdx.x;   // 0..55
  int n = blockIdx.y;   // 0..124
  const float* g0 = G + (size_t)(n * 8 + TUP[t][0]) * NCOLS;
  const float* g1 = G + (size_t)(n * 8 + TUP[t][1]) * NCOLS;
  const float* g2 = G + (size_t)(n * 8 + TUP[t][2]) * NCOLS;
  __shared__ float kbuf[D_OUT];
  __shared__ float red1[256], red2[256];
  int tid = threadIdx.x;
  bool isq = (n >= N_SUPPORT);
  int c = n / SHOT, s = n % SHOT;
  float s1 = 0.f, s2 = 0.f;
  for (int d = tid; d < D_OUT; d += 256) {
    float kvv = g0[d] + g1[2 * D_OUT + d] + g2[4 * D_OUT + d] + kb[d];
    float vvv = g0[D_OUT + d] + g1[3 * D_OUT + d] + g2[5 * D_OUT + d] + vb[d];
    kbuf[d] = kvv;
    if (isq) {
      qvbf[((size_t)(n - N_SUPPORT) * T_LEN + t) * D_OUT + d] = __float2bfloat16(vvv);
    } else {
      svT[(size_t)c * (D_OUT * KS_PAD) + (size_t)d * KS_PAD + (s * T_LEN + t)] =
          __float2bfloat16(vvv);
    }
    s1 += kvv;
    s2 += kvv * kvv;
  }
  red1[tid] = s1; red2[tid] = s2;
  __syncthreads();
  for (int sft = 128; sft > 0; sft >>= 1) {
    if (tid < sft) { red1[tid] += red1[tid + sft]; red2[tid] += red2[tid + sft]; }
    __syncthreads();
  }
  float mu = red1[0] * (1.0f / D_OUT);
  float var = red2[0] * (1.0f / D_OUT) - mu * mu;
  float rs = rsqrtf(var + 1e-5f);
  __hip_bfloat16* kout = isq ? qkbf + ((size_t)(n - N_SUPPORT) * T_LEN + t) * D_OUT
                             : skbf + ((size_t)(c * KS_PAD + s * T_LEN + t)) * D_OUT;
  for (int d = tid; d < D_OUT; d += 256) {
    kout[d] = __float2bfloat16((kbuf[d] - mu) * rs * lng[d] + lnb[d]);
  }
}

// ---------------- kernel 3: softmax (fp32) + align + sm bf16 -------------
__global__ __launch_bounds__(256) void softmax_align(const float* __restrict__ S,
                                                     __hip_bfloat16* __restrict__ sm,
                                                     float* __restrict__ align_out) {
  __shared__ float pl[4][KS_LEN];
  int wid = threadIdx.x >> 6, lane = threadIdx.x & 63;
  int row = blockIdx.x * 4 + wid;         // 0..27999, class-uniform per block
  const float* src = S + (size_t)row * KS_PAD;
  float v[5];
  float mx = -1e30f;
#pragma unroll
  for (int j = 0; j < 5; ++j) {
    int ks = lane + j * 64;
    v[j] = (ks < KS_LEN) ? src[ks] : -1e30f;
    mx = fmaxf(mx, v[j]);
  }
#pragma unroll
  for (int m = 32; m > 0; m >>= 1) mx = fmaxf(mx, __shfl_xor(mx, m));
  float sum = 0.f;
  float p[5];
#pragma unroll
  for (int j = 0; j < 5; ++j) {
    int ks = lane + j * 64;
    p[j] = (ks < KS_LEN) ? expf(v[j] - mx) : 0.f;
    sum += p[j];
  }
#pragma unroll
  for (int m = 32; m > 0; m >>= 1) sum += __shfl_xor(sum, m);
  float inv = 1.0f / sum;
  __hip_bfloat16* dst = sm + (size_t)row * KS_PAD;
#pragma unroll
  for (int j = 0; j < 5; ++j) {
    int ks = lane + j * 64;
    if (ks < KS_PAD) dst[ks] = __float2bfloat16((ks < KS_LEN) ? p[j] * inv : 0.f);
  }
  int c = row / MQT;
  if (c == WAY - 1) {
#pragma unroll
    for (int j = 0; j < 5; ++j) {
      int ks = lane + j * 64;
      if (ks < KS_LEN) pl[wid][ks] = p[j] * inv;
    }
    __syncthreads();
    if (lane < T_LEN) {
      float a = 0.f;
#pragma unroll
      for (int k = 0; k < SHOT; ++k) a += pl[wid][k * T_LEN + lane];
      int qt = row - (WAY - 1) * MQT;
      align_out[(size_t)(qt / T_LEN) * (T_LEN * T_LEN) + (qt % T_LEN) * T_LEN + lane] = a;
    }
  }
}

// ---------------- kernel 4: logits -----------------------------------
__global__ __launch_bounds__(256) void logits_k(const float* __restrict__ DP,
                                                float* __restrict__ out) {
  __shared__ float red[256];
  int q = blockIdx.x / WAY, c = blockIdx.x % WAY;
  const float* base = DP + ((size_t)c * MQT + q * T_LEN) * NCT;  // 56*18=1008
  int tid = threadIdx.x;
  float s = 0.f;
  for (int i = tid; i < T_LEN * NCT; i += 256) s += base[i];
  red[tid] = s;
  __syncthreads();
  for (int sft = 128; sft > 0; sft >>= 1) {
    if (tid < sft) red[tid] += red[tid + sft];
    __syncthreads();
  }
  if (tid == 0) out[blockIdx.x] = -red[0] * (1.0f / T_LEN);
}

// ---------------- launch ----------------
extern "C" void kernel_launch(void* const* d_in, const int* in_sizes, int n_in,
                              void* d_out, int out_size, void* d_ws, size_t ws_size,
                              hipStream_t stream) {
  const float* sup  = (const float*)d_in[0];
  const float* que  = (const float*)d_in[1];
  const float* k_w  = (const float*)d_in[3];
  const float* k_b  = (const float*)d_in[4];
  const float* v_w  = (const float*)d_in[5];
  const float* v_b  = (const float*)d_in[6];
  const float* ln_g = (const float*)d_in[7];
  const float* ln_b = (const float*)d_in[8];
  float* out = (float*)d_out;

  char* w = (char*)d_ws;
  __hip_bfloat16* Xbf  = (__hip_bfloat16*)(w + 0);           //  4,096,000 B
  __hip_bfloat16* WT   = (__hip_bfloat16*)(w + 4096000);     // 28,311,552 B
  float*          G    = (float*)(w + 32407552);             // 27,648,000 B
  float*          S    = (float*)(w + 0);                    // alias X+WT (32.26 MB)
  __hip_bfloat16* smbf = (__hip_bfloat16*)(w + 32407552);    // alias G (16.1 MB)
  __hip_bfloat16* qkbf = (__hip_bfloat16*)(w + 60055552);    // 12,902,400 B
  __hip_bfloat16* skbf = (__hip_bfloat16*)(w + 72957952);    //  3,317,760 B
  __hip_bfloat16* svT  = (__hip_bfloat16*)(w + 76275712);    //  3,317,760 B
  __hip_bfloat16* qvbf = (__hip_bfloat16*)(w + 79593472);    // 12,902,400 B
  float*          DP   = (float*)(w + 92495872);             //  2,016,000 B

  const float scale = 0.02946278254943948f; // 1/sqrt(1152)

  pe_add<<<dim3(8000), 256, 0, stream>>>(sup, que, Xbf);
  wtrans<<<dim3(108, 32), 256, 0, stream>>>(k_w, v_w, WT);
  gemm_bt<0><<<dim3(16, 108, 1), 256, 0, stream>>>(
      Xbf, WT, G, nullptr, nullptr,
      N_ROWS, NCOLS, D_IN, D_IN, D_IN, NCOLS, 1.0f, 0, 0, 0);
  combine_ln<<<dim3(T_LEN, N_SEQ), 256, 0, stream>>>(
      G, k_b, v_b, ln_g, ln_b, skbf, qkbf, svT, qvbf);
  gemm_bt<1><<<dim3(88, 5, WAY), 256, 0, stream>>>(
      qkbf, skbf, S, nullptr, nullptr,
      MQT, KS_PAD, D_OUT, D_OUT, D_OUT, KS_PAD, scale,
      0, KS_PAD * D_OUT, MQT * KS_PAD);
  softmax_align<<<dim3(7000), 256, 0, stream>>>(S, smbf, out + N_Q * WAY);
  gemm_bt<2><<<dim3(88, NCT, WAY), 256, 0, stream>>>(
      smbf, svT, nullptr, qvbf, DP,
      MQT, D_OUT, KS_PAD, KS_PAD, KS_PAD, 0, 1.0f,
      MQT * KS_PAD, D_OUT * KS_PAD, MQT * NCT);
  logits_k<<<dim3(N_Q * WAY), 256, 0, stream>>>(DP, out);
}

// Round 5
// 235.432 us; speedup vs baseline: 5.9803x; 1.1071x over previous
//
#include <hip/hip_runtime.h>
#include <hip/hip_bf16.h>
#include <math.h>

// ---------------- constants ----------------
#define SEQ_LEN 8
#define D_IN 2048
#define D_OUT 1152
#define WAY 5
#define SHOT 5
#define N_SUPPORT 25
#define N_Q 100
#define N_SEQ 125
#define N_ROWS 1000        // N_SEQ * SEQ_LEN
#define T_LEN 56
#define KS_LEN 280         // SHOT * T_LEN
#define KS_PAD 288         // padded (16- and 32-multiple)
#define NCOLS 6912         // 6 * D_OUT
#define MQT 5600           // N_Q * T_LEN
#define DPC 18             // 9 col-tiles x 2 waves, proto dist partials

typedef __attribute__((ext_vector_type(4))) float f32x4;
typedef __attribute__((ext_vector_type(8))) short bf16x8;

__constant__ int TUP[T_LEN][3] = {
  {0,1,2},{0,1,3},{0,1,4},{0,1,5},{0,1,6},{0,1,7},{0,2,3},{0,2,4},{0,2,5},{0,2,6},
  {0,2,7},{0,3,4},{0,3,5},{0,3,6},{0,3,7},{0,4,5},{0,4,6},{0,4,7},{0,5,6},{0,5,7},
  {0,6,7},{1,2,3},{1,2,4},{1,2,5},{1,2,6},{1,2,7},{1,3,4},{1,3,5},{1,3,6},{1,3,7},
  {1,4,5},{1,4,6},{1,4,7},{1,5,6},{1,5,7},{1,6,7},{2,3,4},{2,3,5},{2,3,6},{2,3,7},
  {2,4,5},{2,4,6},{2,4,7},{2,5,6},{2,5,7},{2,6,7},{3,4,5},{3,4,6},{3,4,7},{3,5,6},
  {3,5,7},{3,6,7},{4,5,6},{4,5,7},{4,6,7},{5,6,7}
};

__device__ __forceinline__ ushort f2bf(float f) {
  union { float f; unsigned u; } v; v.f = f;
  unsigned r = v.u + 0x7FFFu + ((v.u >> 16) & 1u);   // RNE
  return (ushort)(r >> 16);
}
__device__ __forceinline__ float bf2f(ushort u) {
  union { unsigned u; float f; } v; v.u = ((unsigned)u) << 16;
  return v.f;
}
__device__ __forceinline__ void gload16(const void* g, const void* l) {
  __builtin_amdgcn_global_load_lds(
      (const __attribute__((address_space(1))) unsigned int*)g,
      (__attribute__((address_space(3))) unsigned int*)l, 16, 0, 0);
}

// ---------------- kernel 0: Xbf = (input + PE) as bf16 ----------------
__global__ __launch_bounds__(256) void pe_add(const float* __restrict__ sup,
                                              const float* __restrict__ que,
                                              ushort* __restrict__ X) {
  int idx = blockIdx.x * 256 + threadIdx.x;
  if (idx >= N_ROWS * D_IN) return;
  int d = idx & (D_IN - 1);
  int r = idx >> 11;
  int i = r & 7;
  int h2 = d & ~1;
  float freq = expf((float)h2 * (-9.210340371976184f / (float)D_IN)); // ln(10000)
  float ang = (float)i * freq;
  float pe = ((d & 1) ? cosf(ang) : sinf(ang)) * 0.1f;
  float src = (r < N_SUPPORT * SEQ_LEN) ? sup[idx] : que[idx - N_SUPPORT * SEQ_LEN * D_IN];
  X[idx] = f2bf(src + pe);
}

// ---------------- kernel 1: WT[b*1152+n][k] = W_b[k][n] (bf16) -----------
__global__ __launch_bounds__(256) void wtrans(const float* __restrict__ kw,
                                              const float* __restrict__ vw,
                                              ushort* __restrict__ WT) {
  __shared__ float tile[64][65];
  int bx = blockIdx.x;              // 108 n-tiles (6 b-blocks x 18)
  int by = blockIdx.y;              // 32 k-tiles
  int b = bx / 18;
  int n0 = (bx % 18) * 64;
  int k0 = by * 64;
  const float* src = ((b & 1) ? vw : kw) + (size_t)(b >> 1) * D_IN * D_OUT;
#pragma unroll
  for (int it = 0; it < 16; ++it) {
    int lin = it * 256 + threadIdx.x;
    int kk = lin >> 6, nn = lin & 63;
    tile[kk][nn] = src[(size_t)(k0 + kk) * D_OUT + n0 + nn];
  }
  __syncthreads();
#pragma unroll
  for (int it = 0; it < 16; ++it) {
    int lin = it * 256 + threadIdx.x;
    int nn = lin >> 6, kk = lin & 63;
    WT[((size_t)(b * D_OUT + n0 + nn)) * D_IN + k0 + kk] = f2bf(tile[kk][nn]);
  }
}

// ---------------- generic bt-form MFMA GEMM (m97 structure) --------------
// 128x128 tile, BK=32, 4 waves 2x2, global_load_lds staging.
// EPI 0: C=A*BT^T. EPI 1: C*alpha. EPI 2: proto + (qv-proto)^2 partials.
template<int EPI>
__global__ __launch_bounds__(256) void gemm_bt(
    const ushort* __restrict__ A, const ushort* __restrict__ BT,
    float* __restrict__ C,
    const ushort* __restrict__ QV, float* __restrict__ DP,
    int M, int N, int K, int lda, int ldb, int ldc, float alpha,
    long batchA, long batchB, long batchC) {
  __shared__ ushort As[128][32];
  __shared__ ushort Bs[128][32];
  int z = blockIdx.z;
  A  += (size_t)z * batchA;
  BT += (size_t)z * batchB;
  if constexpr (EPI < 2) C  += (size_t)z * batchC;
  else                   DP += (size_t)z * batchC;

  int tid = threadIdx.x;
  int wid = tid >> 6, lane = tid & 63;
  int l16 = lane & 15, lk = lane >> 4;
  int wr = wid >> 1, wc = wid & 1;
  int row0 = blockIdx.x * 128, col0 = blockIdx.y * 128;
  int lrow = lane >> 2, lcol = (lane & 3) * 8;

  f32x4 acc[4][4] = {};
  for (int k0 = 0; k0 < K; k0 += 32) {
#pragma unroll
    for (int r = 0; r < 2; ++r) {
      int ca = wid * 2 + r;                         // 0..7, wave-uniform
      int grow = row0 + ca * 16 + lrow;
      grow = grow < M ? grow : M - 1;
      gload16(A + (size_t)grow * lda + k0 + lcol, &As[ca * 16][0]);
      int gcol = col0 + ca * 16 + lrow;
      gcol = gcol < N ? gcol : N - 1;
      gload16(BT + (size_t)gcol * ldb + k0 + lcol, &Bs[ca * 16][0]);
    }
    __syncthreads();
    bf16x8 af[4], bv[4];
#pragma unroll
    for (int m = 0; m < 4; ++m) af[m] = *(const bf16x8*)&As[wr * 64 + m * 16 + l16][lk * 8];
#pragma unroll
    for (int j = 0; j < 4; ++j) bv[j] = *(const bf16x8*)&Bs[wc * 64 + j * 16 + l16][lk * 8];
#pragma unroll
    for (int m = 0; m < 4; ++m)
#pragma unroll
      for (int j = 0; j < 4; ++j)
        acc[m][j] = __builtin_amdgcn_mfma_f32_16x16x32_bf16(af[m], bv[j], acc[m][j], 0, 0, 0);
    __syncthreads();
  }

  if constexpr (EPI < 2) {
#pragma unroll
    for (int m = 0; m < 4; ++m)
#pragma unroll
      for (int j = 0; j < 4; ++j) {
        int col = col0 + wc * 64 + j * 16 + l16;
#pragma unroll
        for (int r = 0; r < 4; ++r) {
          int row = row0 + wr * 64 + m * 16 + lk * 4 + r;
          if (row < M && col < N)
            C[(size_t)row * ldc + col] = (EPI == 1) ? acc[m][j][r] * alpha : acc[m][j][r];
        }
      }
  } else {
    float sq[4][4] = {};
#pragma unroll
    for (int m = 0; m < 4; ++m)
#pragma unroll
      for (int j = 0; j < 4; ++j) {
        int col = col0 + wc * 64 + j * 16 + l16;   // N=1152 exact, no col guard
#pragma unroll
        for (int r = 0; r < 4; ++r) {
          int row = row0 + wr * 64 + m * 16 + lk * 4 + r;
          if (row < M) {
            float qvv = bf2f(QV[(size_t)row * D_OUT + col]);
            float d = qvv - acc[m][j][r];
            sq[m][r] += d * d;
          }
        }
      }
#pragma unroll
    for (int m = 0; m < 4; ++m)
#pragma unroll
      for (int r = 0; r < 4; ++r) {
        sq[m][r] += __shfl_xor(sq[m][r], 1);
        sq[m][r] += __shfl_xor(sq[m][r], 2);
        sq[m][r] += __shfl_xor(sq[m][r], 4);
        sq[m][r] += __shfl_xor(sq[m][r], 8);
      }
    if (l16 == 0) {
#pragma unroll
      for (int m = 0; m < 4; ++m)
#pragma unroll
        for (int r = 0; r < 4; ++r) {
          int row = row0 + wr * 64 + m * 16 + lk * 4 + r;
          if (row < M) DP[(size_t)row * DPC + blockIdx.y * 2 + wc] = sq[m][r];
        }
    }
  }
}

// ---------------- kernel 2: tuple-combine + bias + LayerNorm(K) -----------
__global__ __launch_bounds__(256) void combine_ln(const float* __restrict__ G,
                                                  const float* __restrict__ kb,
                                                  const float* __restrict__ vb,
                                                  const float* __restrict__ lng,
                                                  const float* __restrict__ lnb,
                                                  ushort* __restrict__ skbf,
                                                  ushort* __restrict__ qkbf,
                                                  ushort* __restrict__ sv,
                                                  ushort* __restrict__ qvbf) {
  int t = blockIdx.x;   // 0..55
  int n = blockIdx.y;   // 0..124
  const float* g0 = G + (size_t)(n * 8 + TUP[t][0]) * NCOLS;
  const float* g1 = G + (size_t)(n * 8 + TUP[t][1]) * NCOLS + 2 * D_OUT;
  const float* g2 = G + (size_t)(n * 8 + TUP[t][2]) * NCOLS + 4 * D_OUT;
  __shared__ float kbuf[D_OUT];
  __shared__ float red1[256], red2[256];
  int tid = threadIdx.x;
  bool isq = (n >= N_SUPPORT);
  int c = n / SHOT, s = n % SHOT;
  ushort* vout = isq ? qvbf + ((size_t)(n - N_SUPPORT) * T_LEN + t) * D_OUT
                     : sv + ((size_t)c * KS_PAD + s * T_LEN + t) * D_OUT;
  float s1 = 0.f, s2 = 0.f;
  for (int d4 = tid; d4 < D_OUT / 4; d4 += 256) {
    int d = d4 * 4;
    float4 a = *(const float4*)(g0 + d);
    float4 b = *(const float4*)(g0 + D_OUT + d);
    float4 c1 = *(const float4*)(g1 + d);
    float4 c2 = *(const float4*)(g1 + D_OUT + d);
    float4 e1 = *(const float4*)(g2 + d);
    float4 e2 = *(const float4*)(g2 + D_OUT + d);
    float4 kb4 = *(const float4*)(kb + d);
    float4 vb4 = *(const float4*)(vb + d);
    float kx = a.x + c1.x + e1.x + kb4.x, ky = a.y + c1.y + e1.y + kb4.y;
    float kz = a.z + c1.z + e1.z + kb4.z, kw = a.w + c1.w + e1.w + kb4.w;
    float vx = b.x + c2.x + e2.x + vb4.x, vy = b.y + c2.y + e2.y + vb4.y;
    float vz = b.z + c2.z + e2.z + vb4.z, vw = b.w + c2.w + e2.w + vb4.w;
    *(float4*)(kbuf + d) = make_float4(kx, ky, kz, kw);
    ushort4 vv; vv.x = f2bf(vx); vv.y = f2bf(vy); vv.z = f2bf(vz); vv.w = f2bf(vw);
    *(ushort4*)(vout + d) = vv;
    s1 += kx + ky + kz + kw;
    s2 += kx * kx + ky * ky + kz * kz + kw * kw;
  }
  red1[tid] = s1; red2[tid] = s2;
  __syncthreads();
  for (int sft = 128; sft > 0; sft >>= 1) {
    if (tid < sft) { red1[tid] += red1[tid + sft]; red2[tid] += red2[tid + sft]; }
    __syncthreads();
  }
  float mu = red1[0] * (1.0f / D_OUT);
  float var = red2[0] * (1.0f / D_OUT) - mu * mu;
  float rs = rsqrtf(var + 1e-5f);
  ushort* kout = isq ? qkbf + ((size_t)(n - N_SUPPORT) * T_LEN + t) * D_OUT
                     : skbf + ((size_t)c * KS_PAD + s * T_LEN + t) * D_OUT;
  for (int d4 = tid; d4 < D_OUT / 4; d4 += 256) {
    int d = d4 * 4;
    float4 kv = *(const float4*)(kbuf + d);
    float4 g4 = *(const float4*)(lng + d);
    float4 b4 = *(const float4*)(lnb + d);
    ushort4 o;
    o.x = f2bf((kv.x - mu) * rs * g4.x + b4.x);
    o.y = f2bf((kv.y - mu) * rs * g4.y + b4.y);
    o.z = f2bf((kv.z - mu) * rs * g4.z + b4.z);
    o.w = f2bf((kv.w - mu) * rs * g4.w + b4.w);
    *(ushort4*)(kout + d) = o;
  }
}

// ---------------- kernel 2b: svT[c][d][ks] = sv[c][ks][d], zero pad -------
__global__ __launch_bounds__(256) void svtrans(const ushort* __restrict__ sv,
                                               ushort* __restrict__ svT) {
  __shared__ ushort tile[32][65];
  int c = blockIdx.z;
  int d0 = blockIdx.x * 64;   // 18 tiles
  int k0 = blockIdx.y * 32;   // 9 tiles
  const ushort* src = sv + (size_t)c * KS_PAD * D_OUT;
  ushort* dst = svT + (size_t)c * D_OUT * KS_PAD;
  int tid = threadIdx.x;
#pragma unroll
  for (int it = 0; it < 8; ++it) {
    int lin = it * 256 + tid;
    int ks = k0 + (lin >> 6), d = d0 + (lin & 63);
    tile[lin >> 6][lin & 63] = (ks < KS_LEN) ? src[(size_t)ks * D_OUT + d] : (ushort)0;
  }
  __syncthreads();
#pragma unroll
  for (int it = 0; it < 8; ++it) {
    int lin = it * 256 + tid;
    int d = lin >> 5, ks = lin & 31;
    dst[(size_t)(d0 + d) * KS_PAD + k0 + ks] = tile[ks][d];
  }
}

// ---------------- kernel 3: softmax (fp32) + align + sm bf16 -------------
__global__ __launch_bounds__(256) void softmax_align(const float* __restrict__ S,
                                                     ushort* __restrict__ sm,
                                                     float* __restrict__ align_out) {
  __shared__ float pl[4][KS_LEN];
  int wid = threadIdx.x >> 6, lane = threadIdx.x & 63;
  int row = blockIdx.x * 4 + wid;         // 0..27999
  const float* src = S + (size_t)row * KS_PAD;
  float v[5];
  float mx = -1e30f;
#pragma unroll
  for (int j = 0; j < 5; ++j) {
    int ks = lane + j * 64;
    v[j] = (ks < KS_LEN) ? src[ks] : -1e30f;
    mx = fmaxf(mx, v[j]);
  }
#pragma unroll
  for (int m = 32; m > 0; m >>= 1) mx = fmaxf(mx, __shfl_xor(mx, m));
  float sum = 0.f;
  float p[5];
#pragma unroll
  for (int j = 0; j < 5; ++j) {
    int ks = lane + j * 64;
    p[j] = (ks < KS_LEN) ? expf(v[j] - mx) : 0.f;
    sum += p[j];
  }
#pragma unroll
  for (int m = 32; m > 0; m >>= 1) sum += __shfl_xor(sum, m);
  float inv = 1.0f / sum;
  ushort* dst = sm + (size_t)row * KS_PAD;
#pragma unroll
  for (int j = 0; j < 5; ++j) {
    int ks = lane + j * 64;
    if (ks < KS_PAD) dst[ks] = f2bf((ks < KS_LEN) ? p[j] * inv : 0.f);
  }
  int c = row / MQT;
  if (c == WAY - 1) {
#pragma unroll
    for (int j = 0; j < 5; ++j) {
      int ks = lane + j * 64;
      if (ks < KS_LEN) pl[wid][ks] = p[j] * inv;
    }
    __syncthreads();
    if (lane < T_LEN) {
      float a = 0.f;
#pragma unroll
      for (int k = 0; k < SHOT; ++k) a += pl[wid][k * T_LEN + lane];
      int qt = row - (WAY - 1) * MQT;
      align_out[(size_t)(qt / T_LEN) * (T_LEN * T_LEN) + (qt % T_LEN) * T_LEN + lane] = a;
    }
  }
}

// ---------------- kernel 4: logits -----------------------------------
__global__ __launch_bounds__(256) void logits_k(const float* __restrict__ DP,
                                                float* __restrict__ out) {
  __shared__ float red[256];
  int q = blockIdx.x / WAY, c = blockIdx.x % WAY;
  const float* base = DP + ((size_t)c * MQT + q * T_LEN) * DPC;  // 56*18=1008
  int tid = threadIdx.x;
  float s = 0.f;
  for (int i = tid; i < T_LEN * DPC; i += 256) s += base[i];
  red[tid] = s;
  __syncthreads();
  for (int sft = 128; sft > 0; sft >>= 1) {
    if (tid < sft) red[tid] += red[tid + sft];
    __syncthreads();
  }
  if (tid == 0) out[blockIdx.x] = -red[0] * (1.0f / T_LEN);
}

// ---------------- launch ----------------
extern "C" void kernel_launch(void* const* d_in, const int* in_sizes, int n_in,
                              void* d_out, int out_size, void* d_ws, size_t ws_size,
                              hipStream_t stream) {
  const float* sup  = (const float*)d_in[0];
  const float* que  = (const float*)d_in[1];
  const float* k_w  = (const float*)d_in[3];
  const float* k_b  = (const float*)d_in[4];
  const float* v_w  = (const float*)d_in[5];
  const float* v_b  = (const float*)d_in[6];
  const float* ln_g = (const float*)d_in[7];
  const float* ln_b = (const float*)d_in[8];
  float* out = (float*)d_out;

  char* w = (char*)d_ws;
  // Live ranges allow heavy aliasing; footprint kept at 92.5 MB.
  ushort* Xbf  = (ushort*)(w + 0);            //  4,096,000  (dead after proj)
  ushort* WT   = (ushort*)(w + 4096000);      // 28,311,552  (dead after proj)
  float*  G    = (float*)(w + 32407552);      // 27,648,000  (dead after combine)
  ushort* sv   = (ushort*)(w + 0);            //  3,317,760  (alias Xbf; dead after svtrans)
  float*  S    = (float*)(w + 0);             // 32,256,000  (alias; dead after softmax)
  ushort* smbf = (ushort*)(w + 32407552);     // 16,128,000  (alias G)
  float*  DP   = (float*)(w + 0);             //  2,016,000  (alias S after softmax)
  ushort* qkbf = (ushort*)(w + 60055552);     // 12,902,400
  ushort* skbf = (ushort*)(w + 72957952);     //  3,317,760
  ushort* svT  = (ushort*)(w + 76275712);     //  3,317,760
  ushort* qvbf = (ushort*)(w + 79593472);     // 12,902,400 -> end 92,495,872

  const float scale = 0.02946278254943948f; // 1/sqrt(1152)

  pe_add<<<dim3(8000), 256, 0, stream>>>(sup, que, Xbf);
  wtrans<<<dim3(108, 32), 256, 0, stream>>>(k_w, v_w, WT);
  gemm_bt<0><<<dim3(8, 54, 1), 256, 0, stream>>>(
      Xbf, WT, G, nullptr, nullptr,
      N_ROWS, NCOLS, D_IN, D_IN, D_IN, NCOLS, 1.0f, 0, 0, 0);
  combine_ln<<<dim3(T_LEN, N_SEQ), 256, 0, stream>>>(
      G, k_b, v_b, ln_g, ln_b, skbf, qkbf, sv, qvbf);
  svtrans<<<dim3(18, 9, WAY), 256, 0, stream>>>(sv, svT);
  gemm_bt<1><<<dim3(44, 3, WAY), 256, 0, stream>>>(
      qkbf, skbf, S, nullptr, nullptr,
      MQT, KS_PAD, D_OUT, D_OUT, D_OUT, KS_PAD, scale,
      0, (long)KS_PAD * D_OUT, (long)MQT * KS_PAD);
  softmax_align<<<dim3(7000), 256, 0, stream>>>(S, smbf, out + N_Q * WAY);
  gemm_bt<2><<<dim3(44, 9, WAY), 256, 0, stream>>>(
      smbf, svT, nullptr, qvbf, DP,
      MQT, D_OUT, KS_PAD, KS_PAD, KS_PAD, 0, 1.0f,
      (long)MQT * KS_PAD, (long)D_OUT * KS_PAD, (long)MQT * DPC);
  logits_k<<<dim3(N_Q * WAY), 256, 0, stream>>>(DP, out);
}